// Round 12
// baseline (1327.068 us; speedup 1.0000x reference)
//
#include <hip/hip_runtime.h>
#include <cstring>
#include <cstdio>

typedef __attribute__((ext_vector_type(8))) short short8;
typedef __attribute__((ext_vector_type(4))) float f32x4;
typedef __attribute__((ext_vector_type(4))) unsigned u32x4;

__device__ __forceinline__ short f2bf(float f){
  unsigned u; __builtin_memcpy(&u, &f, 4);
  u += 0x7FFFu + ((u >> 16) & 1u);
  return (short)(u >> 16);
}
__device__ __forceinline__ float bf2f(short s){
  unsigned u = ((unsigned)(unsigned short)s) << 16;
  float f; __builtin_memcpy(&f, &u, 4);
  return f;
}
__device__ __forceinline__ void split2(float v, short& hi, short& lo){
  hi = f2bf(v);
  float r = v - bf2f(hi);   // exact (Sterbenz)
  lo = f2bf(r);
}
__device__ __forceinline__ unsigned pack2(float v){
  short hi, lo; split2(v, hi, lo);
  return (((unsigned)(unsigned short)hi) << 16) | (unsigned)(unsigned short)lo;
}
__device__ __forceinline__ float tanh_fast(float x){
  float e = __expf(2.0f * x);
  return 1.0f - 2.0f / (e + 1.0f);
}

// swizzled LDS short-index for h planes: element (r,k) -> idx, XOR bits 3..5
#define HIDX(r,k) ((((r) * 512) + (k)) ^ (((r) & 7) << 3))

// ---------------------------------------------------------------------------
// K0a: transpose + hi/lo split
// ---------------------------------------------------------------------------
__global__ void transpose_split(const float* __restrict__ in,
                                short* __restrict__ outh, short* __restrict__ outl,
                                int R, int C){
  int idx = blockIdx.x * 256 + threadIdx.x;
  if (idx < R * C){
    int r = idx / C, c = idx % C;
    short h, l; split2(in[(size_t)r * C + c], h, l);
    outh[(size_t)c * R + r] = h;
    outl[(size_t)c * R + r] = l;
  }
}

// K0b: plain transpose to single bf16 (for Wout)
__global__ void transpose_to_bf16(const float* __restrict__ in, short* __restrict__ out,
                                  int R, int C){
  int idx = blockIdx.x * 256 + threadIdx.x;
  if (idx < R * C){
    int r = idx / C, c = idx % C;
    out[(size_t)c * R + r] = f2bf(in[(size_t)r * C + c]);
  }
}

// ---------------------------------------------------------------------------
// K1: x [B=256][D=256][T=256] f32 -> xT_hi/xT_lo [(t*256+b)][d] bf16
// ---------------------------------------------------------------------------
__global__ __launch_bounds__(256) void transpose_x_split(const float* __restrict__ x,
                                                         short* __restrict__ xTh,
                                                         short* __restrict__ xTl){
  __shared__ float tile[64][65];
  const int b = blockIdx.x, d0 = blockIdx.y * 64, t0 = blockIdx.z * 64;
  const int tid = threadIdx.x;
  const float* xp = x + ((size_t)b * 256 + d0) * 256 + t0;
  for (int v = tid; v < 1024; v += 256){
    int r = v >> 4, c4 = (v & 15) * 4;
    float4 f = *(const float4*)(xp + (size_t)r * 256 + c4);
    tile[r][c4+0] = f.x; tile[r][c4+1] = f.y; tile[r][c4+2] = f.z; tile[r][c4+3] = f.w;
  }
  __syncthreads();
  for (int v = tid; v < 512; v += 256){
    int j = v >> 3, i8 = (v & 7) * 8;
    short8 oh, ol;
    #pragma unroll
    for (int u = 0; u < 8; ++u){ short h, l; split2(tile[i8 + u][j], h, l); oh[u] = h; ol[u] = l; }
    size_t off = ((size_t)(t0 + j) * 256 + b) * 256 + d0 + i8;
    *(short8*)(xTh + off) = oh;
    *(short8*)(xTl + off) = ol;
  }
}

// ---------------------------------------------------------------------------
// K2: split-precision GEMM (3-product), 128x128 tile, 4 waves (2x2 of 64x64).
// fp32 output (r2-proven precision for xproj). rows<32768 -> C0 else C1.
// ---------------------------------------------------------------------------
__global__ __launch_bounds__(256) void gemm1_split(
    const short* __restrict__ Ah, const short* __restrict__ Al,
    const short* __restrict__ Bh, const short* __restrict__ Bl,
    const float* __restrict__ bias, float* __restrict__ C0, float* __restrict__ C1,
    int M, int N, int K)
{
  __shared__ short lAh[128][72];
  __shared__ short lAl[128][72];
  __shared__ short lBh[128][72];
  __shared__ short lBl[128][72];
  const int m0 = blockIdx.y * 128, n0 = blockIdx.x * 128;
  const int tid = threadIdx.x;
  const int lane = tid & 63, wave = tid >> 6;
  const int wm = (wave >> 1) * 64, wn = (wave & 1) * 64;
  f32x4 acc[4][4] = {};
  for (int k0 = 0; k0 < K; k0 += 64){
    __syncthreads();
    for (int v = tid; v < 4096; v += 256){
      int sel = v >> 10, idx = v & 1023;
      int r = idx >> 3, c = (idx & 7) * 8;
      const short* src = (sel == 0) ? Ah + (size_t)(m0 + r) * K + k0 + c
                       : (sel == 1) ? Al + (size_t)(m0 + r) * K + k0 + c
                       : (sel == 2) ? Bh + (size_t)(n0 + r) * K + k0 + c
                                    : Bl + (size_t)(n0 + r) * K + k0 + c;
      short8 val = *(const short8*)src;
      short* dst = (sel == 0) ? &lAh[r][c] : (sel == 1) ? &lAl[r][c]
                 : (sel == 2) ? &lBh[r][c] : &lBl[r][c];
      *(short8*)dst = val;
    }
    __syncthreads();
    #pragma unroll
    for (int kk = 0; kk < 64; kk += 32){
      int ko = kk + (lane >> 4) * 8;
      short8 ah[4], al[4], bh[4], bl[4];
      #pragma unroll
      for (int i = 0; i < 4; ++i){
        ah[i] = *(const short8*)&lAh[wm + i * 16 + (lane & 15)][ko];
        al[i] = *(const short8*)&lAl[wm + i * 16 + (lane & 15)][ko];
        bh[i] = *(const short8*)&lBh[wn + i * 16 + (lane & 15)][ko];
        bl[i] = *(const short8*)&lBl[wn + i * 16 + (lane & 15)][ko];
      }
      #pragma unroll
      for (int i = 0; i < 4; ++i)
      #pragma unroll
      for (int j = 0; j < 4; ++j){
        acc[i][j] = __builtin_amdgcn_mfma_f32_16x16x32_bf16(ah[i], bh[j], acc[i][j], 0, 0, 0);
        acc[i][j] = __builtin_amdgcn_mfma_f32_16x16x32_bf16(ah[i], bl[j], acc[i][j], 0, 0, 0);
        acc[i][j] = __builtin_amdgcn_mfma_f32_16x16x32_bf16(al[i], bh[j], acc[i][j], 0, 0, 0);
      }
    }
  }
  const int cr = (lane >> 4) * 4, cc = lane & 15;
  #pragma unroll
  for (int i = 0; i < 4; ++i)
  #pragma unroll
  for (int j = 0; j < 4; ++j){
    int row = m0 + wm + i * 16 + cr;
    int col = n0 + wn + j * 16 + cc;
    float bv = bias[col];
    float* base = (row < 32768) ? C0 : C1;
    int rr = (row < 32768) ? row : row - 32768;
    #pragma unroll
    for (int r = 0; r < 4; ++r){
      base[(size_t)(rr + r) * N + col] = acc[i][j][r] + bv;
    }
  }
}

// ---------------------------------------------------------------------------
// K3 v12: v5's exact structure (256 blocks = 32 teams x 8 slices, 8
// block-leader flags, check-then-sleep poll, fp32 xproj loads BEFORE the poll,
// states after flag) + u64 tag-embedded payload (r4-proven) so the producer
// drain is removed (raw s_barrier only), + parity-double-buffered LDS h
// planes (post-unpack barrier is lgkm-only).
// ---------------------------------------------------------------------------
__global__ __launch_bounds__(256, 1) void rnn_steps_v12(
    const float* __restrict__ xp0,    // t<128:  [(t*256+b)][512] f32
    const float* __restrict__ xp1,    // t>=128: [((t-128)*256+b)][512] f32
    const short* __restrict__ WhTh,   // [512][512] bf16 hi, [n][k]
    const short* __restrict__ WhTl,   // [512][512] bf16 lo
    const float* __restrict__ init,   // [512]
    short* __restrict__ states,       // [(b*256+t)][512] bf16
    unsigned long long* __restrict__ pay,  // [2][32][8][512] u64 [tag|payload]
    unsigned* __restrict__ flags)     // [2][32][32] u32 (8 used/team)
{
  __shared__ short hh[2 * 16 * 512];  // parity-double-buffered hi plane
  __shared__ short hl[2 * 16 * 512];  // lo plane; rows 8..15 zero both parities
  const int tid = threadIdx.x, lane = tid & 63, wave = tid >> 6;
  const int team = blockIdx.x & 31, slice = blockIdx.x >> 5;
  const int b0 = team * 8;
  const int nc = slice * 64 + wave * 16;          // this wave's global col base

  // ---- prologue: Wh B-fragments into registers (hi+lo, 16 k-steps) ----
  short8 Bh[16], Bl[16];
  {
    const size_t col = (size_t)(nc + (lane & 15));
    const int kb0 = (lane >> 4) * 8;
    #pragma unroll
    for (int ks = 0; ks < 16; ++ks){
      Bh[ks] = *(const short8*)(WhTh + col * 512 + ks * 32 + kb0);
      Bl[ks] = *(const short8*)(WhTl + col * 512 + ks * 32 + kb0);
    }
    #pragma unroll
    for (int ks = 0; ks < 16; ++ks){
      asm volatile("" : "+v"(Bh[ks]), "+v"(Bl[ks]));
    }
  }
  // zero pad rows 8..15 (both parities); fill rows 0..7 parity0 with init
  for (int v = tid; v < 8 * 512; v += 256){
    int r = 8 + (v >> 9), k = v & 511;
    int ix = HIDX(r, k);
    hh[ix] = 0; hh[8192 + ix] = 0;
    hl[ix] = 0; hl[8192 + ix] = 0;
  }
  for (int v = tid; v < 8 * 512; v += 256){
    int r = v >> 9, k = v & 511;
    short hi, lo; split2(init[k], hi, lo);
    int ix = HIDX(r, k);
    hh[ix] = hi; hl[ix] = lo;
  }
  __syncthreads();

  // ---- per-lane constants (same verified mapping as r2..r5) ----
  const int cc = lane & 15;
  const bool islo = (lane < 32);
  const int mbase = ((lane & 31) >> 4) * 4;
  const int m_0 = mbase + (islo ? 0 : 2);
  const int m_1 = mbase + (islo ? 1 : 3);
  const int n = nc + cc;                           // global col of this lane
  float hr0 = init[n], hr1 = init[n];              // fp32 residual masters

  const int am = lane & 15, kb = (lane >> 4) * 8;
  const int rr = tid >> 5, c0 = (tid & 31) * 16;   // exchange-read assignment

  for (int t = 0; t < 256; ++t){
    // fp32 xproj loads BEFORE the poll (v5 placement: HBM latency hides
    // under detect; first poll round's vmcnt(0) completes them)
    const float* xpb = (t < 128) ? xp0 : xp1;
    const int tt = (t < 128) ? t : t - 128;
    const float xv0 = xpb[((size_t)tt * 256 + b0 + m_0) * 512 + n];
    const float xv1 = xpb[((size_t)tt * 256 + b0 + m_1) * 512 + n];
    const int buf = (t & 1) * 8192;

    if (t > 0){
      const unsigned tagv = (unsigned)t;
      // 1) flag poll (v5 exact: check-then-sleep, one 32B line)
      const unsigned* flg = flags + (((size_t)(t & 1)) * 32 + team) * 32;
      while (true){
        u32x4 f0, f1;
        asm volatile("global_load_dwordx4 %0, %1, off sc0 sc1" : "=&v"(f0) : "v"(flg)     : "memory");
        asm volatile("global_load_dwordx4 %0, %1, off sc0 sc1" : "=&v"(f1) : "v"(flg + 4) : "memory");
        asm volatile("s_waitcnt vmcnt(0)" : "+v"(f0), "+v"(f1) :: "memory");
        if (f0.x >= tagv && f0.y >= tagv && f0.z >= tagv && f0.w >= tagv &&
            f1.x >= tagv && f1.y >= tagv && f1.z >= tagv && f1.w >= tagv) break;
        __builtin_amdgcn_s_sleep(1);
      }
      // 2) tag-verified payload read (r4-proven format; flag-gated so ~1 round)
      const unsigned long long* src =
          pay + ((((size_t)(t & 1)) * 32 + team) * 8 + rr) * 512 + c0;
      u32x4 g[8];
      bool need0 = true, need1 = true, need2 = true, need3 = true;
      bool need4 = true, need5 = true, need6 = true, need7 = true;
      while (true){
        if (need0) asm volatile("global_load_dwordx4 %0, %1, off sc0 sc1" : "=&v"(g[0]) : "v"(src +  0) : "memory");
        if (need1) asm volatile("global_load_dwordx4 %0, %1, off sc0 sc1" : "=&v"(g[1]) : "v"(src +  2) : "memory");
        if (need2) asm volatile("global_load_dwordx4 %0, %1, off sc0 sc1" : "=&v"(g[2]) : "v"(src +  4) : "memory");
        if (need3) asm volatile("global_load_dwordx4 %0, %1, off sc0 sc1" : "=&v"(g[3]) : "v"(src +  6) : "memory");
        if (need4) asm volatile("global_load_dwordx4 %0, %1, off sc0 sc1" : "=&v"(g[4]) : "v"(src +  8) : "memory");
        if (need5) asm volatile("global_load_dwordx4 %0, %1, off sc0 sc1" : "=&v"(g[5]) : "v"(src + 10) : "memory");
        if (need6) asm volatile("global_load_dwordx4 %0, %1, off sc0 sc1" : "=&v"(g[6]) : "v"(src + 12) : "memory");
        if (need7) asm volatile("global_load_dwordx4 %0, %1, off sc0 sc1" : "=&v"(g[7]) : "v"(src + 14) : "memory");
        asm volatile("s_waitcnt vmcnt(0)"
                     : "+v"(g[0]), "+v"(g[1]), "+v"(g[2]), "+v"(g[3]),
                       "+v"(g[4]), "+v"(g[5]), "+v"(g[6]), "+v"(g[7]) :: "memory");
        need0 = (g[0].y != tagv) | (g[0].w != tagv);
        need1 = (g[1].y != tagv) | (g[1].w != tagv);
        need2 = (g[2].y != tagv) | (g[2].w != tagv);
        need3 = (g[3].y != tagv) | (g[3].w != tagv);
        need4 = (g[4].y != tagv) | (g[4].w != tagv);
        need5 = (g[5].y != tagv) | (g[5].w != tagv);
        need6 = (g[6].y != tagv) | (g[6].w != tagv);
        need7 = (g[7].y != tagv) | (g[7].w != tagv);
        if (!(need0 | need1 | need2 | need3 | need4 | need5 | need6 | need7)) break;
        __builtin_amdgcn_s_sleep(1);
      }
      // 3) unpack payloads -> LDS hi/lo planes, parity buf
      short8 h0v, h1v, l0v, l1v;
      #pragma unroll
      for (int i = 0; i < 4; ++i){
        unsigned pa = g[i].x,     pb = g[i].z;      // cols c0+2i, c0+2i+1
        unsigned pc = g[4 + i].x, pd = g[4 + i].z;  // cols c0+8+2i, c0+8+2i+1
        h0v[2*i]   = (short)(pa >> 16); h0v[2*i+1] = (short)(pb >> 16);
        l0v[2*i]   = (short)(pa & 0xffffu); l0v[2*i+1] = (short)(pb & 0xffffu);
        h1v[2*i]   = (short)(pc >> 16); h1v[2*i+1] = (short)(pd >> 16);
        l1v[2*i]   = (short)(pc & 0xffffu); l1v[2*i+1] = (short)(pd & 0xffffu);
      }
      *(short8*)&hh[buf + HIDX(rr, c0)]     = h0v;
      *(short8*)&hh[buf + HIDX(rr, c0 + 8)] = h1v;
      *(short8*)&hl[buf + HIDX(rr, c0)]     = l0v;
      *(short8*)&hl[buf + HIDX(rr, c0 + 8)] = l1v;
      // lgkm-only barrier: LDS consistent; no vmcnt drain on this path
      asm volatile("s_waitcnt lgkmcnt(0)" ::: "memory");
      __builtin_amdgcn_s_barrier();
      __builtin_amdgcn_sched_barrier(0);
    }

    // MFMA: 3 independent accumulator chains (hh, hl, lh)
    f32x4 ahh = {}, ahl = {}, alh = {};
    #pragma unroll
    for (int ks = 0; ks < 16; ++ks){
      short8 Ah = *(const short8*)&hh[buf + HIDX(am, ks * 32 + kb)];
      short8 Al = *(const short8*)&hl[buf + HIDX(am, ks * 32 + kb)];
      ahh = __builtin_amdgcn_mfma_f32_16x16x32_bf16(Ah, Bh[ks], ahh, 0, 0, 0);
      ahl = __builtin_amdgcn_mfma_f32_16x16x32_bf16(Ah, Bl[ks], ahl, 0, 0, 0);
      alh = __builtin_amdgcn_mfma_f32_16x16x32_bf16(Al, Bh[ks], alh, 0, 0, 0);
    }
    const float s0 = ahh[0] + (ahl[0] + alh[0]);
    const float s1 = ahh[1] + (ahl[1] + alh[1]);
    const float s2 = ahh[2] + (ahl[2] + alh[2]);
    const float s3 = ahh[3] + (ahl[3] + alh[3]);
    const float t2 = __shfl(s2, lane ^ 32);
    const float t3 = __shfl(s3, lane ^ 32);
    const float v0 = islo ? s0 : t2;
    const float v1 = islo ? s1 : t3;

    const float hn0 = tanh_fast(xv0 + v0) + hr0;
    const float hn1 = tanh_fast(xv1 + v1) + hr1;
    hr0 = hn0; hr1 = hn1;

    if (t < 255){
      // publish h_{t+1}: tag-embedded u64 stores, NO drain; raw barrier
      // aligns waves (all stores issued) before the leader posts the flag.
      const unsigned tagn = (unsigned)(t + 1);
      unsigned long long* dst =
          pay + ((((size_t)((t + 1) & 1)) * 32 + team) * 8) * 512;
      unsigned long long w0 = (((unsigned long long)tagn) << 32) | pack2(hn0);
      unsigned long long w1 = (((unsigned long long)tagn) << 32) | pack2(hn1);
      unsigned long long* a0 = dst + (size_t)m_0 * 512 + n;
      unsigned long long* a1 = dst + (size_t)m_1 * 512 + n;
      asm volatile("global_store_dwordx2 %0, %1, off sc0 sc1" :: "v"(a0), "v"(w0) : "memory");
      asm volatile("global_store_dwordx2 %0, %1, off sc0 sc1" :: "v"(a1), "v"(w1) : "memory");
      __builtin_amdgcn_s_barrier();   // alignment only — no vmcnt(0) drain
      if (tid == 0){
        unsigned* fdst = flags + (((size_t)((t + 1) & 1)) * 32 + team) * 32 + slice;
        asm volatile("global_store_dword %0, %1, off sc0 sc1" :: "v"(fdst), "v"(tagn) : "memory");
      }
    }
    // states AFTER flag post (off the critical sync chain)
    states[((size_t)(b0 + m_0) * 256 + t) * 512 + n] = f2bf(hn0);
    states[((size_t)(b0 + m_1) * 256 + t) * 512 + n] = f2bf(hn1);
  }
}

// ---------------------------------------------------------------------------
// K4: single-product bf16 GEMM, 128x128 tile, 4 waves (2x2 of 64x64), fp32 out.
// ---------------------------------------------------------------------------
__global__ __launch_bounds__(256) void gemm_bias_f32(
    const short* __restrict__ A, const short* __restrict__ Bt,
    const float* __restrict__ bias, float* __restrict__ C,
    int M, int N, int K)
{
  __shared__ short lA[128][72];
  __shared__ short lB[128][72];
  const int m0 = blockIdx.y * 128, n0 = blockIdx.x * 128;
  const int tid = threadIdx.x;
  const int lane = tid & 63, wave = tid >> 6;
  const int wm = (wave >> 1) * 64, wn = (wave & 1) * 64;
  f32x4 acc[4][4] = {};
  for (int k0 = 0; k0 < K; k0 += 64){
    __syncthreads();
    for (int v = tid; v < 2048; v += 256){
      int sel = v >> 10, idx = v & 1023;
      int r = idx >> 3, c = (idx & 7) * 8;
      const short* src = (sel == 0) ? A + (size_t)(m0 + r) * K + k0 + c
                                    : Bt + (size_t)(n0 + r) * K + k0 + c;
      short8 val = *(const short8*)src;
      short* dst = (sel == 0) ? &lA[r][c] : &lB[r][c];
      *(short8*)dst = val;
    }
    __syncthreads();
    #pragma unroll
    for (int kk = 0; kk < 64; kk += 32){
      int ko = kk + (lane >> 4) * 8;
      short8 a[4], b[4];
      #pragma unroll
      for (int i = 0; i < 4; ++i){
        a[i] = *(const short8*)&lA[wm + i * 16 + (lane & 15)][ko];
        b[i] = *(const short8*)&lB[wn + i * 16 + (lane & 15)][ko];
      }
      #pragma unroll
      for (int i = 0; i < 4; ++i)
      #pragma unroll
      for (int j = 0; j < 4; ++j){
        acc[i][j] = __builtin_amdgcn_mfma_f32_16x16x32_bf16(a[i], b[j], acc[i][j], 0, 0, 0);
      }
    }
  }
  const int cr = (lane >> 4) * 4, cc = lane & 15;
  #pragma unroll
  for (int i = 0; i < 4; ++i)
  #pragma unroll
  for (int j = 0; j < 4; ++j){
    int row = m0 + wm + i * 16 + cr;
    int col = n0 + wn + j * 16 + cc;
    float bv = bias[col];
    #pragma unroll
    for (int r = 0; r < 4; ++r){
      C[(size_t)(row + r) * N + col] = acc[i][j][r] + bv;
    }
  }
}

// ---------------------------------------------------------------------------
extern "C" void kernel_launch(void* const* d_in, const int* in_sizes, int n_in,
                              void* d_out, int out_size, void* d_ws, size_t ws_size,
                              hipStream_t stream){
  (void)in_sizes; (void)n_in; (void)out_size;
  const float* x    = (const float*)d_in[0];
  const float* Wx   = (const float*)d_in[1];
  const float* Wh   = (const float*)d_in[2];
  const float* bias = (const float*)d_in[3];
  const float* Wout = (const float*)d_in[4];
  const float* bout = (const float*)d_in[5];
  const float* init = (const float*)d_in[6];
  float* out = (float*)d_out;

  char* p = (char*)d_ws;
  // [0,64Mi): xT hi+lo during GEMM1, then states (written only by rnn).
  short* xTh    = (short*)(p);
  short* xTl    = (short*)(p + 33554432);
  short* states = (short*)(p);
  // xproj fp32: rows [0,32768) in ws, rows [32768,65536) in d_out (dead until GEMM2).
  float* xproj0 = (float*)(p + 67108864);     // 64 MiB
  float* xproj1 = (float*)d_out;              // 64 MiB
  short* WxTh   = (short*)(p + 134217728);    // 256 KiB
  short* WxTl   = (short*)(p + 134479872);    // 256 KiB
  short* WhTh   = (short*)(p + 134742016);    // 512 KiB
  short* WhTl   = (short*)(p + 135266304);    // 512 KiB
  short* WoutT  = (short*)(p + 135790592);    // 256 KiB
  unsigned long long* pay = (unsigned long long*)(p + 136052736); // 2 MiB [2][32][8][512]
  unsigned* flags = (unsigned*)(p + 138149888); // 8 KiB [2][32][32]
  if (ws_size < 138158080u){
    fprintf(stderr, "kernel_launch: ws_size=%zu < 138158080 needed\n", ws_size);
  }

  // clear pay tags + flags every launch (graph-capture-safe; tags restart at 1
  // each launch so stale tags must be wiped)
  hipMemsetAsync(pay, 0, 2105344, stream);

  transpose_split<<<(256*512 + 255)/256, 256, 0, stream>>>(Wx, WxTh, WxTl, 256, 512);
  transpose_split<<<(512*512 + 255)/256, 256, 0, stream>>>(Wh, WhTh, WhTl, 512, 512);
  transpose_to_bf16<<<(512*256 + 255)/256, 256, 0, stream>>>(Wout, WoutT, 512, 256);
  transpose_x_split<<<dim3(256, 4, 4), 256, 0, stream>>>(x, xTh, xTl);
  // xproj = xT @ Wx + b at ~fp32 precision (3-product split MFMA), 128^2 tile
  gemm1_split<<<dim3(4, 512), 256, 0, stream>>>(xTh, xTl, WxTh, WxTl, bias,
                                                xproj0, xproj1, 65536, 512, 256);
  // recurrence: 32 teams x 8 slices, v12 protocol
  rnn_steps_v12<<<256, 256, 0, stream>>>(xproj0, xproj1, WhTh, WhTl, init,
                                         states, pay, flags);
  // out = states @ Wout + bout (single bf16 product), 128^2 tile
  gemm_bias_f32<<<dim3(2, 512), 256, 0, stream>>>(states, WoutT, bout, out, 65536, 256, 512);
}

// Round 13
// 913.378 us; speedup vs baseline: 1.4529x; 1.4529x over previous
//
#include <hip/hip_runtime.h>
#include <cstring>
#include <cstdio>

typedef __attribute__((ext_vector_type(8))) short short8;
typedef __attribute__((ext_vector_type(4))) float f32x4;
typedef __attribute__((ext_vector_type(4))) unsigned u32x4;

__device__ __forceinline__ short f2bf(float f){
  unsigned u; __builtin_memcpy(&u, &f, 4);
  u += 0x7FFFu + ((u >> 16) & 1u);
  return (short)(u >> 16);
}
__device__ __forceinline__ float bf2f(short s){
  unsigned u = ((unsigned)(unsigned short)s) << 16;
  float f; __builtin_memcpy(&f, &u, 4);
  return f;
}
__device__ __forceinline__ void split2(float v, short& hi, short& lo){
  hi = f2bf(v);
  float r = v - bf2f(hi);   // exact (Sterbenz)
  lo = f2bf(r);
}
__device__ __forceinline__ unsigned pack2(float v){
  short hi, lo; split2(v, hi, lo);
  return (((unsigned)(unsigned short)hi) << 16) | (unsigned)(unsigned short)lo;
}
__device__ __forceinline__ float tanh_fast(float x){
  float e = __expf(2.0f * x);
  return 1.0f - 2.0f / (e + 1.0f);
}

// swizzled LDS short-index for h planes: element (r,k) -> idx, XOR bits 3..5
#define HIDX(r,k) ((((r) * 512) + (k)) ^ (((r) & 7) << 3))

// ---------------------------------------------------------------------------
// K0a: transpose + hi/lo split: outh[c][r] + outl[c][r] = split(in[r][c])
// ---------------------------------------------------------------------------
__global__ void transpose_split(const float* __restrict__ in,
                                short* __restrict__ outh, short* __restrict__ outl,
                                int R, int C){
  int idx = blockIdx.x * 256 + threadIdx.x;
  if (idx < R * C){
    int r = idx / C, c = idx % C;
    short h, l; split2(in[(size_t)r * C + c], h, l);
    outh[(size_t)c * R + r] = h;
    outl[(size_t)c * R + r] = l;
  }
}

// K0b: plain transpose to single bf16 (for Wout)
__global__ void transpose_to_bf16(const float* __restrict__ in, short* __restrict__ out,
                                  int R, int C){
  int idx = blockIdx.x * 256 + threadIdx.x;
  if (idx < R * C){
    int r = idx / C, c = idx % C;
    out[(size_t)c * R + r] = f2bf(in[(size_t)r * C + c]);
  }
}

// ---------------------------------------------------------------------------
// K1: x [B=256][D=256][T=256] f32 -> xT_hi/xT_lo [(t*256+b)][d] bf16
// ---------------------------------------------------------------------------
__global__ __launch_bounds__(256) void transpose_x_split(const float* __restrict__ x,
                                                         short* __restrict__ xTh,
                                                         short* __restrict__ xTl){
  __shared__ float tile[64][65];
  const int b = blockIdx.x, d0 = blockIdx.y * 64, t0 = blockIdx.z * 64;
  const int tid = threadIdx.x;
  const float* xp = x + ((size_t)b * 256 + d0) * 256 + t0;
  for (int v = tid; v < 1024; v += 256){
    int r = v >> 4, c4 = (v & 15) * 4;
    float4 f = *(const float4*)(xp + (size_t)r * 256 + c4);
    tile[r][c4+0] = f.x; tile[r][c4+1] = f.y; tile[r][c4+2] = f.z; tile[r][c4+3] = f.w;
  }
  __syncthreads();
  for (int v = tid; v < 512; v += 256){
    int j = v >> 3, i8 = (v & 7) * 8;
    short8 oh, ol;
    #pragma unroll
    for (int u = 0; u < 8; ++u){ short h, l; split2(tile[i8 + u][j], h, l); oh[u] = h; ol[u] = l; }
    size_t off = ((size_t)(t0 + j) * 256 + b) * 256 + d0 + i8;
    *(short8*)(xTh + off) = oh;
    *(short8*)(xTl + off) = ol;
  }
}

// ---------------------------------------------------------------------------
// K2: split-precision GEMM (3-product): C = (Ah+Al)@(Bh+Bl)^T + bias, fp32 out.
// Output rows < 32768 -> C0, else C1 (row-32768).
// ---------------------------------------------------------------------------
__global__ __launch_bounds__(256) void gemm1_split(
    const short* __restrict__ Ah, const short* __restrict__ Al,
    const short* __restrict__ Bh, const short* __restrict__ Bl,
    const float* __restrict__ bias, float* __restrict__ C0, float* __restrict__ C1,
    int M, int N, int K)
{
  __shared__ short lAh[64][72];
  __shared__ short lAl[64][72];
  __shared__ short lBh[64][72];
  __shared__ short lBl[64][72];
  const int m0 = blockIdx.y * 64, n0 = blockIdx.x * 64;
  const int tid = threadIdx.x;
  const int lane = tid & 63, wave = tid >> 6;
  const int wm = (wave >> 1) * 32, wn = (wave & 1) * 32;
  f32x4 acc[2][2] = {};
  for (int k0 = 0; k0 < K; k0 += 64){
    __syncthreads();
    for (int v = tid; v < 2048; v += 256){
      int sel = v >> 9, idx = v & 511;
      int r = idx >> 3, c = (idx & 7) * 8;
      const short* src = (sel == 0) ? Ah + (size_t)(m0 + r) * K + k0 + c
                       : (sel == 1) ? Al + (size_t)(m0 + r) * K + k0 + c
                       : (sel == 2) ? Bh + (size_t)(n0 + r) * K + k0 + c
                                    : Bl + (size_t)(n0 + r) * K + k0 + c;
      short8 val = *(const short8*)src;
      short* dst = (sel == 0) ? &lAh[r][c] : (sel == 1) ? &lAl[r][c]
                 : (sel == 2) ? &lBh[r][c] : &lBl[r][c];
      *(short8*)dst = val;
    }
    __syncthreads();
    #pragma unroll
    for (int kk = 0; kk < 64; kk += 32){
      int ko = kk + (lane >> 4) * 8;
      short8 ah0 = *(const short8*)&lAh[wm +      (lane & 15)][ko];
      short8 ah1 = *(const short8*)&lAh[wm + 16 + (lane & 15)][ko];
      short8 al0 = *(const short8*)&lAl[wm +      (lane & 15)][ko];
      short8 al1 = *(const short8*)&lAl[wm + 16 + (lane & 15)][ko];
      short8 bh0 = *(const short8*)&lBh[wn +      (lane & 15)][ko];
      short8 bh1 = *(const short8*)&lBh[wn + 16 + (lane & 15)][ko];
      short8 bl0 = *(const short8*)&lBl[wn +      (lane & 15)][ko];
      short8 bl1 = *(const short8*)&lBl[wn + 16 + (lane & 15)][ko];
      acc[0][0] = __builtin_amdgcn_mfma_f32_16x16x32_bf16(ah0, bh0, acc[0][0], 0, 0, 0);
      acc[0][1] = __builtin_amdgcn_mfma_f32_16x16x32_bf16(ah0, bh1, acc[0][1], 0, 0, 0);
      acc[1][0] = __builtin_amdgcn_mfma_f32_16x16x32_bf16(ah1, bh0, acc[1][0], 0, 0, 0);
      acc[1][1] = __builtin_amdgcn_mfma_f32_16x16x32_bf16(ah1, bh1, acc[1][1], 0, 0, 0);
      acc[0][0] = __builtin_amdgcn_mfma_f32_16x16x32_bf16(ah0, bl0, acc[0][0], 0, 0, 0);
      acc[0][1] = __builtin_amdgcn_mfma_f32_16x16x32_bf16(ah0, bl1, acc[0][1], 0, 0, 0);
      acc[1][0] = __builtin_amdgcn_mfma_f32_16x16x32_bf16(ah1, bl0, acc[1][0], 0, 0, 0);
      acc[1][1] = __builtin_amdgcn_mfma_f32_16x16x32_bf16(ah1, bl1, acc[1][1], 0, 0, 0);
      acc[0][0] = __builtin_amdgcn_mfma_f32_16x16x32_bf16(al0, bh0, acc[0][0], 0, 0, 0);
      acc[0][1] = __builtin_amdgcn_mfma_f32_16x16x32_bf16(al0, bh1, acc[0][1], 0, 0, 0);
      acc[1][0] = __builtin_amdgcn_mfma_f32_16x16x32_bf16(al1, bh0, acc[1][0], 0, 0, 0);
      acc[1][1] = __builtin_amdgcn_mfma_f32_16x16x32_bf16(al1, bh1, acc[1][1], 0, 0, 0);
    }
  }
  const int cr = (lane >> 4) * 4, cc = lane & 15;
  #pragma unroll
  for (int i = 0; i < 2; ++i)
  #pragma unroll
  for (int j = 0; j < 2; ++j){
    int row = m0 + wm + i * 16 + cr;
    int col = n0 + wn + j * 16 + cc;
    float bv = bias[col];
    float* base = (row < 32768) ? C0 : C1;
    int rr = (row < 32768) ? row : row - 32768;
    #pragma unroll
    for (int r = 0; r < 4; ++r){
      base[(size_t)(rr + r) * N + col] = acc[i][j][r] + bv;
    }
  }
}

// ---------------------------------------------------------------------------
// K3 v5: team-parallel recurrence, flag-gated exchange.
// 256 blocks = 32 teams x 8 N-slices. Wh slice pinned in regs. Payload = u32
// (bf16hi|bf16lo), parity double-buffer. Readiness: 1 flag/producer-block,
// posted after per-thread vmcnt(0) drain + block barrier. Readers poll the
// team's 8 flags as two wave-uniform dwordx4 (1 L3 RT/round), then bulk-read
// payload with one vmcnt(0).
// ---------------------------------------------------------------------------
__global__ __launch_bounds__(256, 1) void rnn_steps_v5(
    const float* __restrict__ xp0,    // t<128:  [(t*256+b)][512] f32
    const float* __restrict__ xp1,    // t>=128: [((t-128)*256+b)][512] f32
    const short* __restrict__ WhTh,   // [512][512] bf16 hi, [n][k]
    const short* __restrict__ WhTl,   // [512][512] bf16 lo
    const float* __restrict__ init,   // [512]
    short* __restrict__ states,       // [(b*256+t)][512] bf16
    unsigned* __restrict__ pay,       // [2][32][8][512] u32 payload
    unsigned* __restrict__ flags)     // [2][32][32] u32 (8 used/team, 128B stride)
{
  __shared__ short hh[16 * 512];      // h hi plane, swizzled, rows 8..15 zero
  __shared__ short hl[16 * 512];      // h lo plane
  const int tid = threadIdx.x, lane = tid & 63, wave = tid >> 6;
  const int team = blockIdx.x & 31, slice = blockIdx.x >> 5;
  const int b0 = team * 8;
  const int nc = slice * 64 + wave * 16;          // this wave's global col base

  // ---- prologue: Wh B-fragments into registers (hi+lo, 16 k-steps) ----
  short8 Bh[16], Bl[16];
  {
    const size_t col = (size_t)(nc + (lane & 15));
    const int kb = (lane >> 4) * 8;
    #pragma unroll
    for (int ks = 0; ks < 16; ++ks){
      Bh[ks] = *(const short8*)(WhTh + col * 512 + ks * 32 + kb);
      Bl[ks] = *(const short8*)(WhTl + col * 512 + ks * 32 + kb);
    }
    #pragma unroll
    for (int ks = 0; ks < 16; ++ks){
      asm volatile("" : "+v"(Bh[ks]), "+v"(Bl[ks]));
    }
  }
  // zero pad rows 8..15 once; fill rows 0..7 with init
  for (int v = tid; v < 8 * 512; v += 256){
    int r = 8 + (v >> 9), k = v & 511;
    hh[HIDX(r, k)] = 0; hl[HIDX(r, k)] = 0;
  }
  for (int v = tid; v < 8 * 512; v += 256){
    int r = v >> 9, k = v & 511;
    short hi, lo; split2(init[k], hi, lo);
    hh[HIDX(r, k)] = hi; hl[HIDX(r, k)] = lo;
  }
  __syncthreads();

  // ---- per-lane epilogue constants (same mapping as verified r2..r4) ----
  const int cc = lane & 15;
  const bool islo = (lane < 32);
  const int mbase = ((lane & 31) >> 4) * 4;
  const int m_0 = mbase + (islo ? 0 : 2);
  const int m_1 = mbase + (islo ? 1 : 3);
  const int n = nc + cc;                           // global col of this lane
  float hr0 = init[n], hr1 = init[n];              // fp32 residual masters

  const int am = lane & 15, kb = (lane >> 4) * 8;
  const int rr = tid >> 5, c0 = (tid & 31) * 16;   // exchange-read assignment

  for (int t = 0; t < 256; ++t){
    // prefetch xproj for this lane's two elements (overlaps poll)
    const float* xpb = (t < 128) ? xp0 : xp1;
    const int tt = (t < 128) ? t : t - 128;
    const float xv0 = xpb[((size_t)tt * 256 + b0 + m_0) * 512 + n];
    const float xv1 = xpb[((size_t)tt * 256 + b0 + m_1) * 512 + n];

    if (t > 0){
      const unsigned tagv = (unsigned)t;
      // 1) poll this team's 8 flags (one 32B line, wave-uniform address)
      const unsigned* flg = flags + (((size_t)(t & 1)) * 32 + team) * 32;
      u32x4 f0, f1;
      while (true){
        asm volatile("global_load_dwordx4 %0, %1, off sc0 sc1" : "=&v"(f0) : "v"(flg)     : "memory");
        asm volatile("global_load_dwordx4 %0, %1, off sc0 sc1" : "=&v"(f1) : "v"(flg + 4) : "memory");
        asm volatile("s_waitcnt vmcnt(0)" : "+v"(f0), "+v"(f1) :: "memory");
        if (f0.x >= tagv && f0.y >= tagv && f0.z >= tagv && f0.w >= tagv &&
            f1.x >= tagv && f1.y >= tagv && f1.z >= tagv && f1.w >= tagv) break;
        __builtin_amdgcn_s_sleep(1);
      }
      // 2) bulk payload read: row rr, cols c0..c0+15 (64B), one vmcnt(0)
      const unsigned* src = pay + ((((size_t)(t & 1)) * 32 + team) * 8 + rr) * 512 + c0;
      u32x4 g0, g1, g2, g3;
      asm volatile("global_load_dwordx4 %0, %1, off sc0 sc1" : "=&v"(g0) : "v"(src +  0) : "memory");
      asm volatile("global_load_dwordx4 %0, %1, off sc0 sc1" : "=&v"(g1) : "v"(src +  4) : "memory");
      asm volatile("global_load_dwordx4 %0, %1, off sc0 sc1" : "=&v"(g2) : "v"(src +  8) : "memory");
      asm volatile("global_load_dwordx4 %0, %1, off sc0 sc1" : "=&v"(g3) : "v"(src + 12) : "memory");
      asm volatile("s_waitcnt vmcnt(0)"
                   : "+v"(g0), "+v"(g1), "+v"(g2), "+v"(g3) :: "memory");
      // 3) unpack -> LDS hi/lo planes
      short8 h0v, h1v, l0v, l1v;
      // cols c0+0..3 = g0, c0+4..7 = g1, c0+8..11 = g2, c0+12..15 = g3
      h0v[0] = (short)(g0.x >> 16); h0v[1] = (short)(g0.y >> 16);
      h0v[2] = (short)(g0.z >> 16); h0v[3] = (short)(g0.w >> 16);
      h0v[4] = (short)(g1.x >> 16); h0v[5] = (short)(g1.y >> 16);
      h0v[6] = (short)(g1.z >> 16); h0v[7] = (short)(g1.w >> 16);
      h1v[0] = (short)(g2.x >> 16); h1v[1] = (short)(g2.y >> 16);
      h1v[2] = (short)(g2.z >> 16); h1v[3] = (short)(g2.w >> 16);
      h1v[4] = (short)(g3.x >> 16); h1v[5] = (short)(g3.y >> 16);
      h1v[6] = (short)(g3.z >> 16); h1v[7] = (short)(g3.w >> 16);
      l0v[0] = (short)(g0.x & 0xffffu); l0v[1] = (short)(g0.y & 0xffffu);
      l0v[2] = (short)(g0.z & 0xffffu); l0v[3] = (short)(g0.w & 0xffffu);
      l0v[4] = (short)(g1.x & 0xffffu); l0v[5] = (short)(g1.y & 0xffffu);
      l0v[6] = (short)(g1.z & 0xffffu); l0v[7] = (short)(g1.w & 0xffffu);
      l1v[0] = (short)(g2.x & 0xffffu); l1v[1] = (short)(g2.y & 0xffffu);
      l1v[2] = (short)(g2.z & 0xffffu); l1v[3] = (short)(g2.w & 0xffffu);
      l1v[4] = (short)(g3.x & 0xffffu); l1v[5] = (short)(g3.y & 0xffffu);
      l1v[6] = (short)(g3.z & 0xffffu); l1v[7] = (short)(g3.w & 0xffffu);
      *(short8*)&hh[HIDX(rr, c0)]     = h0v;
      *(short8*)&hh[HIDX(rr, c0 + 8)] = h1v;
      *(short8*)&hl[HIDX(rr, c0)]     = l0v;
      *(short8*)&hl[HIDX(rr, c0 + 8)] = l1v;
      __syncthreads();
    }

    // MFMA: 3 independent accumulator chains (hh, hl, lh)
    f32x4 ahh = {}, ahl = {}, alh = {};
    #pragma unroll
    for (int ks = 0; ks < 16; ++ks){
      short8 Ah = *(const short8*)&hh[HIDX(am, ks * 32 + kb)];
      short8 Al = *(const short8*)&hl[HIDX(am, ks * 32 + kb)];
      ahh = __builtin_amdgcn_mfma_f32_16x16x32_bf16(Ah, Bh[ks], ahh, 0, 0, 0);
      ahl = __builtin_amdgcn_mfma_f32_16x16x32_bf16(Ah, Bl[ks], ahl, 0, 0, 0);
      alh = __builtin_amdgcn_mfma_f32_16x16x32_bf16(Al, Bh[ks], alh, 0, 0, 0);
    }
    const float s0 = ahh[0] + (ahl[0] + alh[0]);
    const float s1 = ahh[1] + (ahl[1] + alh[1]);
    const float s2 = ahh[2] + (ahl[2] + alh[2]);
    const float s3 = ahh[3] + (ahl[3] + alh[3]);
    const float t2 = __shfl(s2, lane ^ 32);
    const float t3 = __shfl(s3, lane ^ 32);
    const float v0 = islo ? s0 : t2;
    const float v1 = islo ? s1 : t3;

    const float hn0 = tanh_fast(xv0 + v0) + hr0;
    const float hn1 = tanh_fast(xv1 + v1) + hr1;
    hr0 = hn0; hr1 = hn1;

    if (t < 255){
      // publish payload for h_{t+1} (parity (t+1)&1)
      unsigned* dst = pay + ((((size_t)((t + 1) & 1)) * 32 + team) * 8) * 512;
      unsigned w0 = pack2(hn0), w1 = pack2(hn1);
      unsigned* a0 = dst + (size_t)m_0 * 512 + n;
      unsigned* a1 = dst + (size_t)m_1 * 512 + n;
      asm volatile("global_store_dword %0, %1, off sc0 sc1" :: "v"(a0), "v"(w0) : "memory");
      asm volatile("global_store_dword %0, %1, off sc0 sc1" :: "v"(a1), "v"(w1) : "memory");
    }
    // states write (plain)
    states[((size_t)(b0 + m_0) * 256 + t) * 512 + n] = f2bf(hn0);
    states[((size_t)(b0 + m_1) * 256 + t) * 512 + n] = f2bf(hn1);

    if (t < 255){
      // drain own stores (payload ack'd at coherence point), then block
      // barrier, then leader posts the flag for step t+1.
      asm volatile("s_waitcnt vmcnt(0)" ::: "memory");
      __syncthreads();
      if (tid == 0){
        unsigned* fdst = flags + (((size_t)((t + 1) & 1)) * 32 + team) * 32 + slice;
        unsigned tagn = (unsigned)(t + 1);
        asm volatile("global_store_dword %0, %1, off sc0 sc1" :: "v"(fdst), "v"(tagn) : "memory");
      }
    }
  }
}

// ---------------------------------------------------------------------------
// K4: single-precision bf16 GEMM for the output projection (fp32 out).
// ---------------------------------------------------------------------------
__global__ __launch_bounds__(256) void gemm_bias_f32(
    const short* __restrict__ A, const short* __restrict__ Bt,
    const float* __restrict__ bias, float* __restrict__ C,
    int M, int N, int K)
{
  __shared__ short lA[64][72];
  __shared__ short lB[64][72];
  const int m0 = blockIdx.y * 64, n0 = blockIdx.x * 64;
  const int tid = threadIdx.x;
  const int lane = tid & 63, wave = tid >> 6;
  const int wm = (wave >> 1) * 32, wn = (wave & 1) * 32;
  f32x4 acc[2][2] = {};
  for (int k0 = 0; k0 < K; k0 += 64){
    __syncthreads();
    for (int v = tid; v < 512; v += 256){
      int r = v >> 3, c = v & 7;
      *(short8*)&lA[r][c*8] = *(const short8*)(A + (size_t)(m0 + r) * K + k0 + c*8);
      *(short8*)&lB[r][c*8] = *(const short8*)(Bt + (size_t)(n0 + r) * K + k0 + c*8);
    }
    __syncthreads();
    #pragma unroll
    for (int kk = 0; kk < 64; kk += 32){
      int ko = kk + (lane >> 4) * 8;
      short8 a0 = *(const short8*)&lA[wm +      (lane & 15)][ko];
      short8 a1 = *(const short8*)&lA[wm + 16 + (lane & 15)][ko];
      short8 b0 = *(const short8*)&lB[wn +      (lane & 15)][ko];
      short8 b1 = *(const short8*)&lB[wn + 16 + (lane & 15)][ko];
      acc[0][0] = __builtin_amdgcn_mfma_f32_16x16x32_bf16(a0, b0, acc[0][0], 0, 0, 0);
      acc[0][1] = __builtin_amdgcn_mfma_f32_16x16x32_bf16(a0, b1, acc[0][1], 0, 0, 0);
      acc[1][0] = __builtin_amdgcn_mfma_f32_16x16x32_bf16(a1, b0, acc[1][0], 0, 0, 0);
      acc[1][1] = __builtin_amdgcn_mfma_f32_16x16x32_bf16(a1, b1, acc[1][1], 0, 0, 0);
    }
  }
  const int cr = (lane >> 4) * 4, cc = lane & 15;
  #pragma unroll
  for (int i = 0; i < 2; ++i)
  #pragma unroll
  for (int j = 0; j < 2; ++j){
    int row = m0 + wm + i * 16 + cr;
    int col = n0 + wn + j * 16 + cc;
    float bv = bias[col];
    #pragma unroll
    for (int r = 0; r < 4; ++r){
      C[(size_t)(row + r) * N + col] = acc[i][j][r] + bv;
    }
  }
}

// ---------------------------------------------------------------------------
extern "C" void kernel_launch(void* const* d_in, const int* in_sizes, int n_in,
                              void* d_out, int out_size, void* d_ws, size_t ws_size,
                              hipStream_t stream){
  (void)in_sizes; (void)n_in; (void)out_size;
  const float* x    = (const float*)d_in[0];
  const float* Wx   = (const float*)d_in[1];
  const float* Wh   = (const float*)d_in[2];
  const float* bias = (const float*)d_in[3];
  const float* Wout = (const float*)d_in[4];
  const float* bout = (const float*)d_in[5];
  const float* init = (const float*)d_in[6];
  float* out = (float*)d_out;

  char* p = (char*)d_ws;
  // [0,64Mi): xT hi+lo during GEMM1, then states (written only by rnn).
  short* xTh    = (short*)(p);
  short* xTl    = (short*)(p + 33554432);
  short* states = (short*)(p);
  // xproj fp32: rows [0,32768) in ws, rows [32768,65536) in d_out (dead until GEMM2).
  float* xproj0 = (float*)(p + 67108864);     // 64 MiB
  float* xproj1 = (float*)d_out;              // 64 MiB
  short* WxTh   = (short*)(p + 134217728);    // 256 KiB
  short* WxTl   = (short*)(p + 134479872);    // 256 KiB
  short* WhTh   = (short*)(p + 134742016);    // 512 KiB
  short* WhTl   = (short*)(p + 135266304);    // 512 KiB
  short* WoutT  = (short*)(p + 135790592);    // 256 KiB
  unsigned* pay   = (unsigned*)(p + 136052736); // 1 MiB  [2][32][8][512] u32
  unsigned* flags = (unsigned*)(p + 137101312); // 8 KiB  [2][32][32] u32
  if (ws_size < 137109504u){
    fprintf(stderr, "kernel_launch: ws_size=%zu < 137109504 needed\n", ws_size);
  }

  // clear flags every launch (graph-capture-safe); payload gated by flags
  hipMemsetAsync(flags, 0, 8192, stream);

  transpose_split<<<(256*512 + 255)/256, 256, 0, stream>>>(Wx, WxTh, WxTl, 256, 512);
  transpose_split<<<(512*512 + 255)/256, 256, 0, stream>>>(Wh, WhTh, WhTl, 512, 512);
  transpose_to_bf16<<<(512*256 + 255)/256, 256, 0, stream>>>(Wout, WoutT, 512, 256);
  transpose_x_split<<<dim3(256, 4, 4), 256, 0, stream>>>(x, xTh, xTl);
  // xproj = xT @ Wx + b at ~fp32 precision (3-product split MFMA)
  gemm1_split<<<dim3(8, 1024), 256, 0, stream>>>(xTh, xTl, WxTh, WxTl, bias,
                                                 xproj0, xproj1, 65536, 512, 256);
  // recurrence: 32 teams x 8 slices, flag-gated exchange
  rnn_steps_v5<<<256, 256, 0, stream>>>(xproj0, xproj1, WhTh, WhTl, init,
                                        states, pay, flags);
  // out = states @ Wout + bout (single bf16 product)
  gemm_bias_f32<<<dim3(4, 1024), 256, 0, stream>>>(states, WoutT, bout, out, 65536, 256, 512);
}